// Round 1
// baseline (6587.350 us; speedup 1.0000x reference)
//
#include <hip/hip_runtime.h>

#define B_ 64
#define S_ 1024
#define I_ 512
#define H_ 512
#define SH_ (S_ * H_)
#define OUT_H (B_ * SH_)

// ---------------------------------------------------------------------------
// Kernel 1: x_proj GEMM.  out[m,n] = sum_k A[m,k]*W[n,k] + bih[n] + bhh[n]
// 128x128 tile, BK=16, 256 threads, 8x8 micro-tile, fp32 vector ALU.
// (unchanged from previous round)
// ---------------------------------------------------------------------------
__global__ __launch_bounds__(256) void xproj_kernel(
    const float* __restrict__ A, const float* __restrict__ W,
    const float* __restrict__ bih, const float* __restrict__ bhh,
    float* __restrict__ out)
{
  __shared__ float As[16][132];
  __shared__ float Bs[16][132];
  const int tid = threadIdx.x;
  const int m0 = blockIdx.x * 128;
  const int n0 = blockIdx.y * 128;

  float acc[8][8];
  #pragma unroll
  for (int i = 0; i < 8; ++i)
    #pragma unroll
    for (int j = 0; j < 8; ++j) acc[i][j] = 0.f;

  const int mb = (tid >> 4) * 8;
  const int nb = (tid & 15) * 8;

  for (int kb = 0; kb < I_ / 16; ++kb) {
    const int k0 = kb * 16;
    __syncthreads();
    #pragma unroll
    for (int l = 0; l < 2; ++l) {
      int s  = tid + l * 256;
      int ml = s >> 2;
      int kc = s & 3;
      float4 av = *(const float4*)(A + (size_t)(m0 + ml) * I_ + k0 + kc * 4);
      As[kc*4+0][ml] = av.x; As[kc*4+1][ml] = av.y;
      As[kc*4+2][ml] = av.z; As[kc*4+3][ml] = av.w;
      float4 bv = *(const float4*)(W + (size_t)(n0 + ml) * I_ + k0 + kc * 4);
      Bs[kc*4+0][ml] = bv.x; Bs[kc*4+1][ml] = bv.y;
      Bs[kc*4+2][ml] = bv.z; Bs[kc*4+3][ml] = bv.w;
    }
    __syncthreads();
    #pragma unroll
    for (int k = 0; k < 16; ++k) {
      float4 a0 = *(const float4*)&As[k][mb];
      float4 a1 = *(const float4*)&As[k][mb + 4];
      float4 b0 = *(const float4*)&Bs[k][nb];
      float4 b1 = *(const float4*)&Bs[k][nb + 4];
      float a[8] = {a0.x,a0.y,a0.z,a0.w,a1.x,a1.y,a1.z,a1.w};
      float b[8] = {b0.x,b0.y,b0.z,b0.w,b1.x,b1.y,b1.z,b1.w};
      #pragma unroll
      for (int i = 0; i < 8; ++i)
        #pragma unroll
        for (int j = 0; j < 8; ++j) acc[i][j] += a[i] * b[j];
    }
  }

  float bias[8];
  #pragma unroll
  for (int j = 0; j < 8; ++j) bias[j] = bih[n0 + nb + j] + bhh[n0 + nb + j];
  #pragma unroll
  for (int i = 0; i < 8; ++i) {
    float4 v0 = make_float4(acc[i][0]+bias[0], acc[i][1]+bias[1],
                            acc[i][2]+bias[2], acc[i][3]+bias[3]);
    float4 v1 = make_float4(acc[i][4]+bias[4], acc[i][5]+bias[5],
                            acc[i][6]+bias[6], acc[i][7]+bias[7]);
    float* o = out + (size_t)(m0 + mb + i) * H_ + n0 + nb;
    *(float4*)o       = v0;
    *(float4*)(o + 4) = v1;
  }
}

// ---------------------------------------------------------------------------
// Kernel 2: init — zero tag-slot 0.  (d_ws re-poisoned to 0xAA per launch.)
// Slot0's first tagged write (h_2) carries tag 1, poison bit31=1 would alias
// it, so slot0 must be cleared; slot1's poison (bit31=1) differs from the
// expected tag 0 at t=1, so it needs no init.  h0 read from d_in at t=0.
// ---------------------------------------------------------------------------
__global__ __launch_bounds__(256) void init_kernel(unsigned* __restrict__ hbu)
{
  int i = blockIdx.x * 256 + threadIdx.x;
  if (i < B_ * H_) hbu[i] = 0u;
}

// ---------------------------------------------------------------------------
// Kernel 3: recurrence — BARRIER-FREE waves.
// R4->R5: the old structure spent ~78% of each step in sync latency
// (2x __syncthreads + WG-wide double spin + a 32-deep serial epilogue
// reduce on the producer path).  New decomposition: 64 groups (1 batch)
// x 4 WGs x 8 waves = 32 waves/batch; each wave owns 16 outputs with the
// FULL K=512 in registers (lane = 4 outputs x 32 k -> Wr[4][32], 128 VGPR).
// Per step each wave, with NO __syncthreads anywhere:
//   1. spin-loads all 512 tagged h values (8 u32/lane, coalesced) -- the
//      wave consumes exactly what it loads, so staging into its PRIVATE
//      LDS region needs no barrier (same-wave DS ops are in-order);
//   2. 128 FMA/lane off broadcast ds_read_b128 (chunks padded to 36
//      floats: kg vs kg+8 share banks = free 2-way conflict only);
//   3. k-reduction via 4-level __shfl_xor tree over lane bits 2..5 (kg)
//      -- replaces LDS round-trip + barrier + 32-add chain;
//   4. lanes 0..3 finalize 4 contiguous outputs each: xp + ReLU, tagged
//      agent store (data-as-flag, tag=(t>>1)&1 in bit31), out store.
// Group WGs {b, b+64, b+128, b+192} are all == b (mod 8) -> same XCD under
// round-robin dispatch, keeping the h handshake in one L2.  Tag protocol
// and the h_{t+2}-cannot-overtake argument are unchanged.  Grid 256 WGs
// x 512 thr, <= 256 CUs -> co-resident -> spins always make progress.
// ---------------------------------------------------------------------------
__global__ __launch_bounds__(512, 2) void recur_kernel(
    const float* __restrict__ Whh, const float* __restrict__ h0,
    float* __restrict__ out, unsigned* __restrict__ hbu)
{
  const int tid   = threadIdx.x;
  const int lane  = tid & 63;
  const int w     = tid >> 6;           // wave in WG, 0..7
  const int b     = blockIdx.x & 63;    // batch
  const int sub   = blockIdx.x >> 6;    // 0..3
  const int wv    = sub * 8 + w;        // wave in batch group, 0..31
  const int obase = wv * 16;            // 16 outputs per wave
  const int og    = lane & 3;           // output sub-group (4 outputs)
  const int kg    = lane >> 2;          // k-chunk 0..15 (32 k each)

  __shared__ float hsh[8][16 * 36];     // per-wave staged h, +4 pad/chunk

  // Weights: rows obase+og*4+i, cols kg*32..+32 -> 128 VGPR per lane.
  float Wr[4][32];
  #pragma unroll
  for (int i = 0; i < 4; ++i) {
    const float4* wrow =
        (const float4*)(Whh + (size_t)(obase + og * 4 + i) * H_ + kg * 32);
    #pragma unroll
    for (int j = 0; j < 8; ++j) {
      float4 w4 = wrow[j];
      Wr[i][4*j+0] = w4.x; Wr[i][4*j+1] = w4.y;
      Wr[i][4*j+2] = w4.z; Wr[i][4*j+3] = w4.w;
    }
  }

  float* hls  = &hsh[w][0];
  float* outp = out + (size_t)b * SH_ + obase + og * 4;   // lanes 0..3 only

  for (int t = 0; t < S_; ++t) {
    // xp prefetch for the finalist lanes (latency hides under the spin)
    float4 xp = make_float4(0.f, 0.f, 0.f, 0.f);
    if (lane < 4) xp = *(const float4*)outp;

    // ---- stage h_t into this wave's private LDS region ----
    if (t == 0) {
      const float* hp = h0 + b * H_;
      #pragma unroll
      for (int j = 0; j < 8; ++j) {
        int e = lane + 64 * j;
        hls[(e >> 5) * 36 + (e & 31)] = hp[e];
      }
    } else {
      const unsigned* hs = hbu + (t & 1) * (B_ * H_) + b * H_;
      const unsigned expct = ((unsigned)t >> 1) & 1u;
      unsigned a[8];
      #pragma unroll
      for (int j = 0; j < 8; ++j)
        a[j] = __hip_atomic_load(hs + lane + 64 * j, __ATOMIC_RELAXED,
                                 __HIP_MEMORY_SCOPE_AGENT);
      #pragma unroll
      for (int j = 0; j < 8; ++j) {
        while ((a[j] >> 31) != expct) {
          __builtin_amdgcn_s_sleep(1);
          a[j] = __hip_atomic_load(hs + lane + 64 * j, __ATOMIC_RELAXED,
                                   __HIP_MEMORY_SCOPE_AGENT);
        }
        int e = lane + 64 * j;
        hls[(e >> 5) * 36 + (e & 31)] = __uint_as_float(a[j] & 0x7fffffffu);
      }
    }
    // same-wave write->read: order DS ops, no barrier needed
    asm volatile("s_waitcnt lgkmcnt(0)" ::: "memory");

    // ---- 128 FMA/lane: 4 outputs x 32 k, broadcast float4 LDS reads ----
    float ac[4] = {0.f, 0.f, 0.f, 0.f};
    const float* hc = hls + kg * 36;
    #pragma unroll
    for (int j4 = 0; j4 < 8; ++j4) {
      float4 hv = *(const float4*)(hc + 4 * j4);
      #pragma unroll
      for (int i = 0; i < 4; ++i) {
        ac[i] += hv.x * Wr[i][4*j4+0];
        ac[i] += hv.y * Wr[i][4*j4+1];
        ac[i] += hv.z * Wr[i][4*j4+2];
        ac[i] += hv.w * Wr[i][4*j4+3];
      }
    }

    // ---- k-reduce over kg (lane bits 2..5) via shuffle tree ----
    #pragma unroll
    for (int i = 0; i < 4; ++i) {
      float r = ac[i];
      r += __shfl_xor(r, 4);
      r += __shfl_xor(r, 8);
      r += __shfl_xor(r, 16);
      r += __shfl_xor(r, 32);
      ac[i] = r;
    }

    // ---- finalize: lanes 0..3 own outputs obase+og*4 .. +3 ----
    if (lane < 4) {
      float4 v;
      v.x = fmaxf(xp.x + ac[0], 0.f);
      v.y = fmaxf(xp.y + ac[1], 0.f);
      v.z = fmaxf(xp.z + ac[2], 0.f);
      v.w = fmaxf(xp.w + ac[3], 0.f);
      const unsigned tg = ((((unsigned)(t + 1)) >> 1) & 1u) << 31;
      unsigned* hd = hbu + ((t + 1) & 1) * (B_ * H_) + b * H_
                   + obase + og * 4;
      __hip_atomic_store(hd + 0, __float_as_uint(v.x) | tg,
                         __ATOMIC_RELAXED, __HIP_MEMORY_SCOPE_AGENT);
      __hip_atomic_store(hd + 1, __float_as_uint(v.y) | tg,
                         __ATOMIC_RELAXED, __HIP_MEMORY_SCOPE_AGENT);
      __hip_atomic_store(hd + 2, __float_as_uint(v.z) | tg,
                         __ATOMIC_RELAXED, __HIP_MEMORY_SCOPE_AGENT);
      __hip_atomic_store(hd + 3, __float_as_uint(v.w) | tg,
                         __ATOMIC_RELAXED, __HIP_MEMORY_SCOPE_AGENT);
      *(float4*)outp = v;                       // out[b,t,:] = h_{t+1}
      if (t == S_ - 1)
        *(float4*)(out + (size_t)OUT_H + b * H_ + obase + og * 4) = v;
      outp += H_;
    }
  }
}

// ---------------------------------------------------------------------------
extern "C" void kernel_launch(void* const* d_in, const int* in_sizes, int n_in,
                              void* d_out, int out_size, void* d_ws, size_t ws_size,
                              hipStream_t stream)
{
  const float* inputs = (const float*)d_in[0];  // [B,S,I]
  const float* h0     = (const float*)d_in[1];  // [1,B,H]
  const float* w_ih   = (const float*)d_in[2];  // [H,I]
  const float* w_hh   = (const float*)d_in[3];  // [H,H]
  const float* b_ih   = (const float*)d_in[4];  // [H]
  const float* b_hh   = (const float*)d_in[5];  // [H]
  float* out = (float*)d_out;                   // [B,S,H] ++ [1,B,H] h_final

  unsigned* hbu = (unsigned*)d_ws;              // 2 tagged h slots

  dim3 g1(512, 4);
  xproj_kernel<<<g1, 256, 0, stream>>>(inputs, w_ih, b_ih, b_hh, out);
  init_kernel<<<128, 256, 0, stream>>>(hbu);
  recur_kernel<<<256, 512, 0, stream>>>(w_hh, h0, out, hbu);
}

// Round 3
// 5275.521 us; speedup vs baseline: 1.2487x; 1.2487x over previous
//
#include <hip/hip_runtime.h>

#define B_ 64
#define S_ 1024
#define I_ 512
#define H_ 512
#define SH_ (S_ * H_)
#define OUT_H (B_ * SH_)
#define BH_ (B_ * H_)

// ---------------------------------------------------------------------------
// Kernel 1: x_proj GEMM.  out[m,n] = sum_k A[m,k]*W[n,k] + bih[n] + bhh[n]
// 128x128 tile, BK=16, 256 threads, 8x8 micro-tile, fp32 vector ALU.
// (unchanged)
// ---------------------------------------------------------------------------
__global__ __launch_bounds__(256) void xproj_kernel(
    const float* __restrict__ A, const float* __restrict__ W,
    const float* __restrict__ bih, const float* __restrict__ bhh,
    float* __restrict__ out)
{
  __shared__ float As[16][132];
  __shared__ float Bs[16][132];
  const int tid = threadIdx.x;
  const int m0 = blockIdx.x * 128;
  const int n0 = blockIdx.y * 128;

  float acc[8][8];
  #pragma unroll
  for (int i = 0; i < 8; ++i)
    #pragma unroll
    for (int j = 0; j < 8; ++j) acc[i][j] = 0.f;

  const int mb = (tid >> 4) * 8;
  const int nb = (tid & 15) * 8;

  for (int kb = 0; kb < I_ / 16; ++kb) {
    const int k0 = kb * 16;
    __syncthreads();
    #pragma unroll
    for (int l = 0; l < 2; ++l) {
      int s  = tid + l * 256;
      int ml = s >> 2;
      int kc = s & 3;
      float4 av = *(const float4*)(A + (size_t)(m0 + ml) * I_ + k0 + kc * 4);
      As[kc*4+0][ml] = av.x; As[kc*4+1][ml] = av.y;
      As[kc*4+2][ml] = av.z; As[kc*4+3][ml] = av.w;
      float4 bv = *(const float4*)(W + (size_t)(n0 + ml) * I_ + k0 + kc * 4);
      Bs[kc*4+0][ml] = bv.x; Bs[kc*4+1][ml] = bv.y;
      Bs[kc*4+2][ml] = bv.z; Bs[kc*4+3][ml] = bv.w;
    }
    __syncthreads();
    #pragma unroll
    for (int k = 0; k < 16; ++k) {
      float4 a0 = *(const float4*)&As[k][mb];
      float4 a1 = *(const float4*)&As[k][mb + 4];
      float4 b0 = *(const float4*)&Bs[k][nb];
      float4 b1 = *(const float4*)&Bs[k][nb + 4];
      float a[8] = {a0.x,a0.y,a0.z,a0.w,a1.x,a1.y,a1.z,a1.w};
      float b[8] = {b0.x,b0.y,b0.z,b0.w,b1.x,b1.y,b1.z,b1.w};
      #pragma unroll
      for (int i = 0; i < 8; ++i)
        #pragma unroll
        for (int j = 0; j < 8; ++j) acc[i][j] += a[i] * b[j];
    }
  }

  float bias[8];
  #pragma unroll
  for (int j = 0; j < 8; ++j) bias[j] = bih[n0 + nb + j] + bhh[n0 + nb + j];
  #pragma unroll
  for (int i = 0; i < 8; ++i) {
    float4 v0 = make_float4(acc[i][0]+bias[0], acc[i][1]+bias[1],
                            acc[i][2]+bias[2], acc[i][3]+bias[3]);
    float4 v1 = make_float4(acc[i][4]+bias[4], acc[i][5]+bias[5],
                            acc[i][6]+bias[6], acc[i][7]+bias[7]);
    float* o = out + (size_t)(m0 + mb + i) * H_ + n0 + nb;
    *(float4*)o       = v0;
    *(float4*)(o + 4) = v1;
  }
}

// ---------------------------------------------------------------------------
// Kernel 2: init — zero tag-slot 0.  (d_ws re-poisoned to 0xAA per launch.)
// Slot0's first tagged write (h_2) carries tag 1; poison bit31=1 would alias
// it, so slot0 must be cleared.  Slot1's poison (bit31=1) differs from the
// expected tag 0 at t=1, so it needs no init.  h0 read from d_in at t=0.
// ---------------------------------------------------------------------------
__global__ __launch_bounds__(256) void init_kernel(unsigned* __restrict__ hbu)
{
  int i = blockIdx.x * 256 + threadIdx.x;
  if (i < BH_) hbu[i] = 0u;
}

// ---------------------------------------------------------------------------
// DPP wave-row reduction helpers (VALU pipe, not DS).  ctrl is a template
// param so it is guaranteed a literal.  xor1, xor2, half-row mirror
// (xor4-equiv after xor1/2), row mirror (xor8-equiv) -> every lane of each
// 16-lane row holds the row sum.
// ---------------------------------------------------------------------------
template <int CTRL>
__device__ __forceinline__ float dpp_add(float x) {
  return x + __int_as_float(__builtin_amdgcn_update_dpp(
      0, __float_as_int(x), CTRL, 0xF, 0xF, true));
}
__device__ __forceinline__ float rowsum16(float x) {
  x = dpp_add<0xB1>(x);    // quad_perm [1,0,3,2]  : xor1
  x = dpp_add<0x4E>(x);    // quad_perm [2,3,0,1]  : xor2
  x = dpp_add<0x141>(x);   // row_half_mirror      : xor4-equiv
  x = dpp_add<0x140>(x);   // row_mirror           : xor8-equiv
  return x;
}

#define FMA4(A, W4, s) \
  A.x += W4.x * (s); A.y += W4.y * (s); A.z += W4.z * (s); A.w += W4.w * (s)
#define FMA8(A, L, Hh) \
  FMA4(A, wv0, L.x);  FMA4(A, wv1, L.y);  FMA4(A, wv2, L.z);  FMA4(A, wv3, L.w); \
  FMA4(A, wv4, Hh.x); FMA4(A, wv5, Hh.y); FMA4(A, wv6, Hh.z); FMA4(A, wv7, Hh.w)

// ---------------------------------------------------------------------------
// Kernel 3: recurrence.  R4/R5 post-mortem: the weight panel NEVER lived in
// registers (VGPR_Count 52/92 < panel size) -> per-step scratch/L2 streaming
// of W dominated.  Fix: W is 32 floats/lane in 8 NAMED float4 SSA values
// (no arrays -> no SROA failure), loaded once before the t-loop.
//   Geometry: 256 WGs = 16 batch-groups (bg=blockIdx&15, batches 4bg..4bg+3;
//   group's 16 WGs all == bg (mod 16) -> same XCD under round-robin) x 16
//   output-slices.  Wave w owns outputs ob..ob+3; lane = k-chunk of 8.
//   Per step: tagged-spin stage h (4 dwords/thread) into bank-balanced
//   [kq][b][8] LDS (double-buffered -> ONE __syncthreads/step); 8x
//   ds_read_b128/lane; 128 FMA into 4 named float4 accs; k-reduce via 4 DPP
//   stages + one per-wave 64-float LDS transpose + 4 adds; finalist lanes
//   0..15 do xp+ReLU and the tagged data-as-flag store (R4 protocol).
// R6 hardening: ReLU is ternary (never -0.0) AND the tagged store masks
// bit31 explicitly (a -0.0 sign bit would corrupt the tag -> consumer
// livelock).  launch_bounds(512,1): 256-VGPR cap, no silent spill;
// occupancy target is 1 WG/CU (grid == 256 == CU count, co-resident).
// ---------------------------------------------------------------------------
__global__ __launch_bounds__(512, 1) void recur_kernel(
    const float* __restrict__ Whh, const float* __restrict__ h0,
    float* __restrict__ out, unsigned* __restrict__ hbu)
{
  const int tid  = threadIdx.x;
  const int lane = tid & 63;
  const int w    = tid >> 6;            // wave id 0..7
  const int bg   = blockIdx.x & 15;     // batch group: batches 4bg..4bg+3
  const int ns   = blockIdx.x >> 4;     // output slice: [32ns, 32ns+32)
  const int b0   = bg * 4;
  const int ob   = ns * 32 + w * 4;     // this wave's 4 output rows

  __shared__ float hsh[2][64 * 36];     // staged h: [buf][kq*36 + b*8 + j]
  __shared__ float redw[8][64];         // per-wave transpose scratch

  // ---- W panel: rows ob..ob+3, cols [8*lane, 8*lane+8) -> 8 named float4
  const float* wp = Whh + (size_t)ob * H_ + lane * 8;
  float4 r0a = *(const float4*)(wp           );
  float4 r0b = *(const float4*)(wp        + 4);
  float4 r1a = *(const float4*)(wp +   H_    );
  float4 r1b = *(const float4*)(wp +   H_ + 4);
  float4 r2a = *(const float4*)(wp + 2*H_    );
  float4 r2b = *(const float4*)(wp + 2*H_ + 4);
  float4 r3a = *(const float4*)(wp + 3*H_    );
  float4 r3b = *(const float4*)(wp + 3*H_ + 4);
  // transpose to j-major, float4 over the 4 output rows:
  float4 wv0 = make_float4(r0a.x, r1a.x, r2a.x, r3a.x);
  float4 wv1 = make_float4(r0a.y, r1a.y, r2a.y, r3a.y);
  float4 wv2 = make_float4(r0a.z, r1a.z, r2a.z, r3a.z);
  float4 wv3 = make_float4(r0a.w, r1a.w, r2a.w, r3a.w);
  float4 wv4 = make_float4(r0b.x, r1b.x, r2b.x, r3b.x);
  float4 wv5 = make_float4(r0b.y, r1b.y, r2b.y, r3b.y);
  float4 wv6 = make_float4(r0b.z, r1b.z, r2b.z, r3b.z);
  float4 wv7 = make_float4(r0b.w, r1b.w, r2b.w, r3b.w);

  // staging write base: element e=tid -> word (e>>3)*36 + (e&7), +8 per batch
  const int swb = (tid >> 3) * 36 + (tid & 7);

  // finalist mapping (lanes 0..15): pair a=lane -> batch b0+(a>>2), out ob+(a&3)
  const int fb = b0 + ((lane >> 2) & 3);
  const int fo = ob + (lane & 3);
  float* outp = out + (size_t)fb * SH_ + fo;           // advances by H_ / step
  unsigned* hdb = hbu + (size_t)fb * H_ + fo;          // + slot*BH_

  for (int t = 0; t < S_; ++t) {
    // xp prefetch for finalist lanes (overlaps the staging spin)
    float xp = 0.f;
    if (lane < 16) xp = *outp;

    // ---- stage h_t into LDS buffer (t&1) ----
    float* hb = &hsh[t & 1][0];
    if (t == 0) {
      const float* hp = h0 + (size_t)b0 * H_ + tid;
      hb[swb     ] = hp[0];
      hb[swb +  8] = hp[H_];
      hb[swb + 16] = hp[2 * H_];
      hb[swb + 24] = hp[3 * H_];
    } else {
      const unsigned* hs = hbu + (t & 1) * BH_ + (size_t)b0 * H_ + tid;
      const unsigned expct = ((unsigned)t >> 1) & 1u;
      unsigned a0 = __hip_atomic_load(hs,        __ATOMIC_RELAXED, __HIP_MEMORY_SCOPE_AGENT);
      unsigned a1 = __hip_atomic_load(hs +   H_, __ATOMIC_RELAXED, __HIP_MEMORY_SCOPE_AGENT);
      unsigned a2 = __hip_atomic_load(hs + 2*H_, __ATOMIC_RELAXED, __HIP_MEMORY_SCOPE_AGENT);
      unsigned a3 = __hip_atomic_load(hs + 3*H_, __ATOMIC_RELAXED, __HIP_MEMORY_SCOPE_AGENT);
      while ((a0 >> 31) != expct) {
        __builtin_amdgcn_s_sleep(1);
        a0 = __hip_atomic_load(hs,        __ATOMIC_RELAXED, __HIP_MEMORY_SCOPE_AGENT);
      }
      while ((a1 >> 31) != expct) {
        __builtin_amdgcn_s_sleep(1);
        a1 = __hip_atomic_load(hs +   H_, __ATOMIC_RELAXED, __HIP_MEMORY_SCOPE_AGENT);
      }
      while ((a2 >> 31) != expct) {
        __builtin_amdgcn_s_sleep(1);
        a2 = __hip_atomic_load(hs + 2*H_, __ATOMIC_RELAXED, __HIP_MEMORY_SCOPE_AGENT);
      }
      while ((a3 >> 31) != expct) {
        __builtin_amdgcn_s_sleep(1);
        a3 = __hip_atomic_load(hs + 3*H_, __ATOMIC_RELAXED, __HIP_MEMORY_SCOPE_AGENT);
      }
      hb[swb     ] = __uint_as_float(a0 & 0x7fffffffu);
      hb[swb +  8] = __uint_as_float(a1 & 0x7fffffffu);
      hb[swb + 16] = __uint_as_float(a2 & 0x7fffffffu);
      hb[swb + 24] = __uint_as_float(a3 & 0x7fffffffu);
    }
    __syncthreads();                 // the only barrier per step (dbuf LDS)

    // ---- 128 FMA/lane: 4 batches x 4 outputs x 8 k (ds_read_b128 x8) ----
    const float* hr = hb + lane * 36;
    float4 hA0 = *(const float4*)(hr     );
    float4 hA1 = *(const float4*)(hr +  4);
    float4 hB0 = *(const float4*)(hr +  8);
    float4 hB1 = *(const float4*)(hr + 12);
    float4 hC0 = *(const float4*)(hr + 16);
    float4 hC1 = *(const float4*)(hr + 20);
    float4 hD0 = *(const float4*)(hr + 24);
    float4 hD1 = *(const float4*)(hr + 28);

    float4 aA = make_float4(0.f, 0.f, 0.f, 0.f);
    float4 aB = make_float4(0.f, 0.f, 0.f, 0.f);
    float4 aC = make_float4(0.f, 0.f, 0.f, 0.f);
    float4 aD = make_float4(0.f, 0.f, 0.f, 0.f);
    FMA8(aA, hA0, hA1);
    FMA8(aB, hB0, hB1);
    FMA8(aC, hC0, hC1);
    FMA8(aD, hD0, hD1);

    // ---- k-reduce: DPP row sums (VALU pipe), 16 scalars ----
    aA.x = rowsum16(aA.x); aA.y = rowsum16(aA.y);
    aA.z = rowsum16(aA.z); aA.w = rowsum16(aA.w);
    aB.x = rowsum16(aB.x); aB.y = rowsum16(aB.y);
    aB.z = rowsum16(aB.z); aB.w = rowsum16(aB.w);
    aC.x = rowsum16(aC.x); aC.y = rowsum16(aC.y);
    aC.z = rowsum16(aC.z); aC.w = rowsum16(aC.w);
    aD.x = rowsum16(aD.x); aD.y = rowsum16(aD.y);
    aD.z = rowsum16(aD.z); aD.w = rowsum16(aD.w);

    // lane l (row r=l>>4, slot a=l&15) contributes pair #a's row-r partial
    const int sa = lane & 15;
    float4 ab = (sa >> 2) == 0 ? aA : (sa >> 2) == 1 ? aB
              : (sa >> 2) == 2 ? aC : aD;
    float sel = (sa & 3) == 0 ? ab.x : (sa & 3) == 1 ? ab.y
              : (sa & 3) == 2 ? ab.z : ab.w;
    redw[w][lane] = sel;
    asm volatile("s_waitcnt lgkmcnt(0)" ::: "memory");  // same-wave wr->rd
    __builtin_amdgcn_sched_barrier(0);

    // ---- finalize: lanes 0..15, one (batch, output) pair each ----
    if (lane < 16) {
      float s = redw[w][lane] + redw[w][lane + 16]
              + redw[w][lane + 32] + redw[w][lane + 48];
      float pre = xp + s;
      float v = pre > 0.f ? pre : 0.f;           // ternary: never -0.0
      const unsigned tg = ((((unsigned)(t + 1)) >> 1) & 1u) << 31;
      __hip_atomic_store(hdb + ((t + 1) & 1) * BH_,
                         (__float_as_uint(v) & 0x7fffffffu) | tg,
                         __ATOMIC_RELAXED, __HIP_MEMORY_SCOPE_AGENT);
      *outp = v;                                  // out[b,t,:] = h_{t+1}
      if (t == S_ - 1)
        out[(size_t)OUT_H + (size_t)fb * H_ + fo] = v;   // h_final
      outp += H_;
    }
    // no second barrier: next step stages into the other LDS buffer, and
    // the staging spin is the inter-WG synchronization point
  }
}

// ---------------------------------------------------------------------------
extern "C" void kernel_launch(void* const* d_in, const int* in_sizes, int n_in,
                              void* d_out, int out_size, void* d_ws, size_t ws_size,
                              hipStream_t stream)
{
  const float* inputs = (const float*)d_in[0];  // [B,S,I]
  const float* h0     = (const float*)d_in[1];  // [1,B,H]
  const float* w_ih   = (const float*)d_in[2];  // [H,I]
  const float* w_hh   = (const float*)d_in[3];  // [H,H]
  const float* b_ih   = (const float*)d_in[4];  // [H]
  const float* b_hh   = (const float*)d_in[5];  // [H]
  float* out = (float*)d_out;                   // [B,S,H] ++ [1,B,H] h_final

  unsigned* hbu = (unsigned*)d_ws;              // 2 tagged h slots

  dim3 g1(512, 4);
  xproj_kernel<<<g1, 256, 0, stream>>>(inputs, w_ih, b_ih, b_hh, out);
  init_kernel<<<128, 256, 0, stream>>>(hbu);
  recur_kernel<<<256, 512, 0, stream>>>(w_hh, h0, out, hbu);
}

// Round 4
// 2177.140 us; speedup vs baseline: 3.0257x; 2.4231x over previous
//
#include <hip/hip_runtime.h>

#define B_ 64
#define S_ 1024
#define I_ 512
#define H_ 512
#define SH_ (S_ * H_)
#define OUT_H (B_ * SH_)
#define BH_ (B_ * H_)

// ---------------------------------------------------------------------------
// Kernel 1: x_proj GEMM.  out[m,n] = sum_k A[m,k]*W[n,k] + bih[n] + bhh[n]
// 128x128 tile, BK=16, 256 threads, 8x8 micro-tile, fp32 vector ALU.
// (unchanged)
// ---------------------------------------------------------------------------
__global__ __launch_bounds__(256) void xproj_kernel(
    const float* __restrict__ A, const float* __restrict__ W,
    const float* __restrict__ bih, const float* __restrict__ bhh,
    float* __restrict__ out)
{
  __shared__ float As[16][132];
  __shared__ float Bs[16][132];
  const int tid = threadIdx.x;
  const int m0 = blockIdx.x * 128;
  const int n0 = blockIdx.y * 128;

  float acc[8][8];
  #pragma unroll
  for (int i = 0; i < 8; ++i)
    #pragma unroll
    for (int j = 0; j < 8; ++j) acc[i][j] = 0.f;

  const int mb = (tid >> 4) * 8;
  const int nb = (tid & 15) * 8;

  for (int kb = 0; kb < I_ / 16; ++kb) {
    const int k0 = kb * 16;
    __syncthreads();
    #pragma unroll
    for (int l = 0; l < 2; ++l) {
      int s  = tid + l * 256;
      int ml = s >> 2;
      int kc = s & 3;
      float4 av = *(const float4*)(A + (size_t)(m0 + ml) * I_ + k0 + kc * 4);
      As[kc*4+0][ml] = av.x; As[kc*4+1][ml] = av.y;
      As[kc*4+2][ml] = av.z; As[kc*4+3][ml] = av.w;
      float4 bv = *(const float4*)(W + (size_t)(n0 + ml) * I_ + k0 + kc * 4);
      Bs[kc*4+0][ml] = bv.x; Bs[kc*4+1][ml] = bv.y;
      Bs[kc*4+2][ml] = bv.z; Bs[kc*4+3][ml] = bv.w;
    }
    __syncthreads();
    #pragma unroll
    for (int k = 0; k < 16; ++k) {
      float4 a0 = *(const float4*)&As[k][mb];
      float4 a1 = *(const float4*)&As[k][mb + 4];
      float4 b0 = *(const float4*)&Bs[k][nb];
      float4 b1 = *(const float4*)&Bs[k][nb + 4];
      float a[8] = {a0.x,a0.y,a0.z,a0.w,a1.x,a1.y,a1.z,a1.w};
      float b[8] = {b0.x,b0.y,b0.z,b0.w,b1.x,b1.y,b1.z,b1.w};
      #pragma unroll
      for (int i = 0; i < 8; ++i)
        #pragma unroll
        for (int j = 0; j < 8; ++j) acc[i][j] += a[i] * b[j];
    }
  }

  float bias[8];
  #pragma unroll
  for (int j = 0; j < 8; ++j) bias[j] = bih[n0 + nb + j] + bhh[n0 + nb + j];
  #pragma unroll
  for (int i = 0; i < 8; ++i) {
    float4 v0 = make_float4(acc[i][0]+bias[0], acc[i][1]+bias[1],
                            acc[i][2]+bias[2], acc[i][3]+bias[3]);
    float4 v1 = make_float4(acc[i][4]+bias[4], acc[i][5]+bias[5],
                            acc[i][6]+bias[6], acc[i][7]+bias[7]);
    float* o = out + (size_t)(m0 + mb + i) * H_ + n0 + nb;
    *(float4*)o       = v0;
    *(float4*)(o + 4) = v1;
  }
}

// ---------------------------------------------------------------------------
// Kernel 2: init — zero tag-slot 0.  (d_ws re-poisoned to 0xAA per launch.)
// Slot0's first tagged write (h_2) carries tag 1; poison bit31=1 would alias
// it, so slot0 must be cleared.  Slot1's poison (bit31=1) differs from the
// expected tag 0 at t=1, so it needs no init.  h0 read from d_in at t=0.
// ---------------------------------------------------------------------------
__global__ __launch_bounds__(256) void init_kernel(unsigned* __restrict__ hbu)
{
  int i = blockIdx.x * 256 + threadIdx.x;
  if (i < BH_) hbu[i] = 0u;
}

// FMA4: acc components are the 4 output rows; W4 is j-major over those rows.
#define FMA4(A, W4, s) \
  A.x += W4.x * (s); A.y += W4.y * (s); A.z += W4.z * (s); A.w += W4.w * (s)
#define FMA16(A, hA, hB, hC, hD) \
  FMA4(A, w00, hA.x); FMA4(A, w01, hA.y); FMA4(A, w02, hA.z); FMA4(A, w03, hA.w); \
  FMA4(A, w04, hB.x); FMA4(A, w05, hB.y); FMA4(A, w06, hB.z); FMA4(A, w07, hB.w); \
  FMA4(A, w08, hC.x); FMA4(A, w09, hC.y); FMA4(A, w10, hC.z); FMA4(A, w11, hC.w); \
  FMA4(A, w12, hD.x); FMA4(A, w13, hD.y); FMA4(A, w14, hD.z); FMA4(A, w15, hD.w)

// ---------------------------------------------------------------------------
// Kernel 3: recurrence — R4 structure restored (proven 1722 us), with the
// R7 post-mortem fix applied IN-PLACE:
//   * R4/R5/R7 all silently streamed W from L2 every step (VGPR_Count
//     52/92/68 < panel size).  R7's VALU-time (VALUBusy x dur) was 2.6x
//     R4's at identical FMA count -> AGPR demotion with per-use
//     v_accvgpr_read.  Root cause: the backend's occupancy heuristic caps
//     VGPRs near 64 unless waves/EU is clamped.  Fix: W held in 16 NAMED
//     float4 SSA values + amdgpu_waves_per_eu(2,2) (we run exactly 8
//     waves/CU = 2/EU; this grants a 256-VGPR budget and disables the
//     heuristic).  Diagnostic: VGPR_Count >= ~100 <=> W truly resident;
//     kills the ~19.7 TB/s L2 W-stream (~55% of R4's step time).
//   * Finalist ROTATION: pair (2r, 2r+1), r = t&3, finalizes step t.  In R4
//     waves 0-1 always carried reduce+store+next-spin serially; rotating
//     gives the next step's finalists a head start on their spin (their
//     loads are already in flight when the producer stores land).
//   * Epilogue 4-way tree sum: 32-deep dependent add chain -> 8+2.
// Geometry, spin protocol, tag scheme, barriers, LDS layouts: R4 verbatim.
// 32 batch-groups (bg=blockIdx&31, batches {2bg,2bg+1}; producer set = 8 WGs
// {bg+32k} all == bg mod 8 -> same XCD) x 8 output-slices of 64.
// Hardening kept: ternary ReLU + explicit bit31 mask on the tagged store.
// ---------------------------------------------------------------------------
__global__ __launch_bounds__(512)
__attribute__((amdgpu_waves_per_eu(2, 2)))
void recur_kernel(
    const float* __restrict__ Whh, const float* __restrict__ h0,
    float* __restrict__ out, unsigned* __restrict__ hbu)
{
  const int tid   = threadIdx.x;
  const int bg    = blockIdx.x & 31;   // batch group: batches {2bg, 2bg+1}
  const int ns    = blockIdx.x >> 5;   // h-slice: outputs [64ns, 64ns+64)
  const int b0    = bg * 2;
  const int obase = ns * 64;
  const int o4    = tid & 15;          // o-block of 4 outputs
  const int kq    = tid >> 4;          // k-chunk: k in [16kq, 16kq+16)
  const int w     = tid >> 6;          // wave id 0..7
  const int lane  = tid & 63;
  const int ep    = w & 1;             // batch within the finalist pair

  __shared__ float hsh[2 * H_];        // staged h, both batches (4 KB)
  __shared__ float red[32][132];       // [kq][b*64 + o_local], padded

  // ---- W panel: rows obase+o4*4+{0..3}, cols 16kq..+16.
  // 16 NAMED float4 SSA values (j-major over the 4 rows) — no arrays, so
  // SROA is trivial; waves_per_eu(2,2) gives the allocator room to keep
  // all 64 floats resident for the whole t-loop.
  const float* wp = Whh + (size_t)(obase + o4 * 4) * H_ + kq * 16;
  float4 r0a = *(const float4*)(wp            );
  float4 r0b = *(const float4*)(wp         + 4);
  float4 r0c = *(const float4*)(wp         + 8);
  float4 r0d = *(const float4*)(wp        + 12);
  float4 r1a = *(const float4*)(wp +   H_     );
  float4 r1b = *(const float4*)(wp +   H_ + 4);
  float4 r1c = *(const float4*)(wp +   H_ + 8);
  float4 r1d = *(const float4*)(wp +   H_ +12);
  float4 r2a = *(const float4*)(wp + 2*H_     );
  float4 r2b = *(const float4*)(wp + 2*H_ + 4);
  float4 r2c = *(const float4*)(wp + 2*H_ + 8);
  float4 r2d = *(const float4*)(wp + 2*H_ +12);
  float4 r3a = *(const float4*)(wp + 3*H_     );
  float4 r3b = *(const float4*)(wp + 3*H_ + 4);
  float4 r3c = *(const float4*)(wp + 3*H_ + 8);
  float4 r3d = *(const float4*)(wp + 3*H_ +12);
  float4 w00 = make_float4(r0a.x, r1a.x, r2a.x, r3a.x);
  float4 w01 = make_float4(r0a.y, r1a.y, r2a.y, r3a.y);
  float4 w02 = make_float4(r0a.z, r1a.z, r2a.z, r3a.z);
  float4 w03 = make_float4(r0a.w, r1a.w, r2a.w, r3a.w);
  float4 w04 = make_float4(r0b.x, r1b.x, r2b.x, r3b.x);
  float4 w05 = make_float4(r0b.y, r1b.y, r2b.y, r3b.y);
  float4 w06 = make_float4(r0b.z, r1b.z, r2b.z, r3b.z);
  float4 w07 = make_float4(r0b.w, r1b.w, r2b.w, r3b.w);
  float4 w08 = make_float4(r0c.x, r1c.x, r2c.x, r3c.x);
  float4 w09 = make_float4(r0c.y, r1c.y, r2c.y, r3c.y);
  float4 w10 = make_float4(r0c.z, r1c.z, r2c.z, r3c.z);
  float4 w11 = make_float4(r0c.w, r1c.w, r2c.w, r3c.w);
  float4 w12 = make_float4(r0d.x, r1d.x, r2d.x, r3d.x);
  float4 w13 = make_float4(r0d.y, r1d.y, r2d.y, r3d.y);
  float4 w14 = make_float4(r0d.z, r1d.z, r2d.z, r3d.z);
  float4 w15 = make_float4(r0d.w, r1d.w, r2d.w, r3d.w);

  // Every thread tracks its finalist output pointer; used 1-of-4 steps.
  float* outp = out + (size_t)(b0 + ep) * SH_ + obase + lane;   // +H_/step
  unsigned* hdb = hbu + (size_t)(b0 + ep) * H_ + obase + lane;  // +slot*BH_

  for (int t = 0; t < S_; ++t) {
    const bool fin = ((w >> 1) == (t & 3));   // rotating finalist pair

    // xp prefetch for this step's finalists (overlaps the staging spin)
    float xp = 0.f;
    if (fin) xp = *outp;

    // ---- stage h_t into LDS (spin on tag for t>=1) — R4 verbatim ----
    if (t == 0) {
      const float* hp = h0 + b0 * H_;
      hsh[tid]       = hp[tid];
      hsh[tid + 512] = hp[tid + 512];
    } else {
      const unsigned* hs = hbu + (t & 1) * BH_ + b0 * H_;
      const unsigned expct = ((unsigned)t >> 1) & 1u;
      unsigned a0 = __hip_atomic_load(hs + tid,       __ATOMIC_RELAXED,
                                      __HIP_MEMORY_SCOPE_AGENT);
      unsigned a1 = __hip_atomic_load(hs + tid + 512, __ATOMIC_RELAXED,
                                      __HIP_MEMORY_SCOPE_AGENT);
      while ((a0 >> 31) != expct) {
        __builtin_amdgcn_s_sleep(1);
        a0 = __hip_atomic_load(hs + tid, __ATOMIC_RELAXED,
                               __HIP_MEMORY_SCOPE_AGENT);
      }
      while ((a1 >> 31) != expct) {
        __builtin_amdgcn_s_sleep(1);
        a1 = __hip_atomic_load(hs + tid + 512, __ATOMIC_RELAXED,
                               __HIP_MEMORY_SCOPE_AGENT);
      }
      hsh[tid]       = __uint_as_float(a0 & 0x7fffffffu);
      hsh[tid + 512] = __uint_as_float(a1 & 0x7fffffffu);
    }
    __syncthreads();                                   // sync 1

    // ---- 128 FMA/thread: 2 batches x 4 outputs x 16 k ----
    const float* hp0 = hsh + kq * 16;
    float4 hA = *(const float4*)(hp0     );
    float4 hB = *(const float4*)(hp0 +  4);
    float4 hC = *(const float4*)(hp0 +  8);
    float4 hD = *(const float4*)(hp0 + 12);
    float4 aA = make_float4(0.f, 0.f, 0.f, 0.f);
    FMA16(aA, hA, hB, hC, hD);

    const float* hp1 = hsh + H_ + kq * 16;
    float4 hE = *(const float4*)(hp1     );
    float4 hF = *(const float4*)(hp1 +  4);
    float4 hG = *(const float4*)(hp1 +  8);
    float4 hH = *(const float4*)(hp1 + 12);
    float4 aB = make_float4(0.f, 0.f, 0.f, 0.f);
    FMA16(aB, hE, hF, hG, hH);

    *(float4*)&red[kq][o4 * 4]      = aA;
    *(float4*)&red[kq][64 + o4 * 4] = aB;
    __syncthreads();                                   // sync 2

    // ---- rotating 2-wave epilogue: tree reduce + ReLU + tagged store ----
    if (fin) {
      const int idx = ep * 64 + lane;
      float s0 = 0.f, s1 = 0.f, s2 = 0.f, s3 = 0.f;
      #pragma unroll
      for (int q = 0; q < 32; q += 4) {
        s0 += red[q    ][idx];
        s1 += red[q + 1][idx];
        s2 += red[q + 2][idx];
        s3 += red[q + 3][idx];
      }
      float pre = xp + ((s0 + s1) + (s2 + s3));
      float v = pre > 0.f ? pre : 0.f;          // ternary: never -0.0
      const unsigned tg = ((((unsigned)(t + 1)) >> 1) & 1u) << 31;
      __hip_atomic_store(hdb + ((t + 1) & 1) * BH_,
                         (__float_as_uint(v) & 0x7fffffffu) | tg,
                         __ATOMIC_RELAXED, __HIP_MEMORY_SCOPE_AGENT);
      *outp = v;                                 // out[b,t,:] = h_{t+1}
      if (t == S_ - 1)
        out[(size_t)OUT_H + (size_t)(b0 + ep) * H_ + obase + lane] = v;
    }
    outp += H_;
    // no sync 3: hsh rewrite is gated by sync2; red rewrite by next sync1;
    // the staging spin is the inter-WG synchronization point
  }
}

// ---------------------------------------------------------------------------
extern "C" void kernel_launch(void* const* d_in, const int* in_sizes, int n_in,
                              void* d_out, int out_size, void* d_ws, size_t ws_size,
                              hipStream_t stream)
{
  const float* inputs = (const float*)d_in[0];  // [B,S,I]
  const float* h0     = (const float*)d_in[1];  // [1,B,H]
  const float* w_ih   = (const float*)d_in[2];  // [H,I]
  const float* w_hh   = (const float*)d_in[3];  // [H,H]
  const float* b_ih   = (const float*)d_in[4];  // [H]
  const float* b_hh   = (const float*)d_in[5];  // [H]
  float* out = (float*)d_out;                   // [B,S,H] ++ [1,B,H] h_final

  unsigned* hbu = (unsigned*)d_ws;              // 2 tagged h slots

  dim3 g1(512, 4);
  xproj_kernel<<<g1, 256, 0, stream>>>(inputs, w_ih, b_ih, b_hh, out);
  init_kernel<<<128, 256, 0, stream>>>(hbu);
  recur_kernel<<<256, 512, 0, stream>>>(w_hh, h0, out, hbu);
}

// Round 5
// 2161.800 us; speedup vs baseline: 3.0472x; 1.0071x over previous
//
#include <hip/hip_runtime.h>

#define B_ 64
#define S_ 1024
#define I_ 512
#define H_ 512
#define SH_ (S_ * H_)
#define OUT_H (B_ * SH_)
#define BH_ (B_ * H_)

// ---------------------------------------------------------------------------
// Kernel 1: x_proj GEMM.  out[m,n] = sum_k A[m,k]*W[n,k] + bih[n] + bhh[n]
// (unchanged)
// ---------------------------------------------------------------------------
__global__ __launch_bounds__(256) void xproj_kernel(
    const float* __restrict__ A, const float* __restrict__ W,
    const float* __restrict__ bih, const float* __restrict__ bhh,
    float* __restrict__ out)
{
  __shared__ float As[16][132];
  __shared__ float Bs[16][132];
  const int tid = threadIdx.x;
  const int m0 = blockIdx.x * 128;
  const int n0 = blockIdx.y * 128;

  float acc[8][8];
  #pragma unroll
  for (int i = 0; i < 8; ++i)
    #pragma unroll
    for (int j = 0; j < 8; ++j) acc[i][j] = 0.f;

  const int mb = (tid >> 4) * 8;
  const int nb = (tid & 15) * 8;

  for (int kb = 0; kb < I_ / 16; ++kb) {
    const int k0 = kb * 16;
    __syncthreads();
    #pragma unroll
    for (int l = 0; l < 2; ++l) {
      int s  = tid + l * 256;
      int ml = s >> 2;
      int kc = s & 3;
      float4 av = *(const float4*)(A + (size_t)(m0 + ml) * I_ + k0 + kc * 4);
      As[kc*4+0][ml] = av.x; As[kc*4+1][ml] = av.y;
      As[kc*4+2][ml] = av.z; As[kc*4+3][ml] = av.w;
      float4 bv = *(const float4*)(W + (size_t)(n0 + ml) * I_ + k0 + kc * 4);
      Bs[kc*4+0][ml] = bv.x; Bs[kc*4+1][ml] = bv.y;
      Bs[kc*4+2][ml] = bv.z; Bs[kc*4+3][ml] = bv.w;
    }
    __syncthreads();
    #pragma unroll
    for (int k = 0; k < 16; ++k) {
      float4 a0 = *(const float4*)&As[k][mb];
      float4 a1 = *(const float4*)&As[k][mb + 4];
      float4 b0 = *(const float4*)&Bs[k][nb];
      float4 b1 = *(const float4*)&Bs[k][nb + 4];
      float a[8] = {a0.x,a0.y,a0.z,a0.w,a1.x,a1.y,a1.z,a1.w};
      float b[8] = {b0.x,b0.y,b0.z,b0.w,b1.x,b1.y,b1.z,b1.w};
      #pragma unroll
      for (int i = 0; i < 8; ++i)
        #pragma unroll
        for (int j = 0; j < 8; ++j) acc[i][j] += a[i] * b[j];
    }
  }

  float bias[8];
  #pragma unroll
  for (int j = 0; j < 8; ++j) bias[j] = bih[n0 + nb + j] + bhh[n0 + nb + j];
  #pragma unroll
  for (int i = 0; i < 8; ++i) {
    float4 v0 = make_float4(acc[i][0]+bias[0], acc[i][1]+bias[1],
                            acc[i][2]+bias[2], acc[i][3]+bias[3]);
    float4 v1 = make_float4(acc[i][4]+bias[4], acc[i][5]+bias[5],
                            acc[i][6]+bias[6], acc[i][7]+bias[7]);
    float* o = out + (size_t)(m0 + mb + i) * H_ + n0 + nb;
    *(float4*)o       = v0;
    *(float4*)(o + 4) = v1;
  }
}

// ---------------------------------------------------------------------------
// Kernel 2: init — zero tag-slot 0.  (d_ws re-poisoned to 0xAA per launch.)
// Slot0's first tagged write (h_2) carries tag 1; poison bit31=1 would alias
// it, so slot0 must be cleared.  Slot1's poison (bit31=1) differs from the
// expected tag 0 at t=1, so it needs no init.  h0 read from d_in at t=0.
// ---------------------------------------------------------------------------
__global__ __launch_bounds__(256) void init_kernel(unsigned* __restrict__ hbu)
{
  int i = blockIdx.x * 256 + threadIdx.x;
  if (i < BH_) hbu[i] = 0u;
}

// FMA4: acc components are the 4 output rows; W4 is j-major over those rows.
#define FMA4(A, W4, s) \
  A.x += W4.x * (s); A.y += W4.y * (s); A.z += W4.z * (s); A.w += W4.w * (s)
#define FMA16(A, hA, hB, hC, hD) \
  FMA4(A, w00, hA.x); FMA4(A, w01, hA.y); FMA4(A, w02, hA.z); FMA4(A, w03, hA.w); \
  FMA4(A, w04, hB.x); FMA4(A, w05, hB.y); FMA4(A, w06, hB.z); FMA4(A, w07, hB.w); \
  FMA4(A, w08, hC.x); FMA4(A, w09, hC.y); FMA4(A, w10, hC.z); FMA4(A, w11, hC.w); \
  FMA4(A, w12, hD.x); FMA4(A, w13, hD.y); FMA4(A, w14, hD.z); FMA4(A, w15, hD.w)

// ---------------------------------------------------------------------------
// Kernel 3: recurrence — R9: WAVE-AUTONOMOUS steps (sync1 deleted).
// R8 post-mortem: W-residency landed (VGPR 88) but only bought 2% -> the
// step is pinned by the handshake skeleton: WG-wide spin gate (slowest of
// 1024 elems, s_sleep(1) 64-cy poll quantum) + serial stage + 2 barriers.
// R9 structural fact: a thread's partial needs only k in [16kq,16kq+16), so
// wave w needs only h[64w..64w+64) per batch == exactly the 128 values its
// own lanes spin-load.  Spin+stage+FMA are wave-local:
//   * each wave proceeds the moment ITS slice is tagged (no sync1, no
//     WG-wide detection tail; same-wave DS ordering covers stage->read);
//   * sync2 (red fan-in) is the ONLY barrier per step;
//   * red is double-buffered [2][32][132] (writes no longer sync1-gated);
//   * busy-poll (no s_sleep) — detect latency beats poll quantum, L2 has
//     spare BW (3% HBM).
// Safety at wave granularity: WG P stores h_{t+2} only after P's sync2(t+1)
// => all P's waves consumed h_{t+1} => C's finalists stored h_{t+1}[C]
// after C's sync2(t) => all C's waves fully consumed h_t.  No
// overwrite-before-read.  Tag protocol verbatim from the proven kernel.
// Kept from R8: W in 16 named float4 SSA + waves_per_eu(2,2) (VGPR 88,
// resident), finalist rotation, tree epilogue, ternary ReLU + bit31 mask.
// ---------------------------------------------------------------------------
__global__ __launch_bounds__(512)
__attribute__((amdgpu_waves_per_eu(2, 2)))
void recur_kernel(
    const float* __restrict__ Whh, const float* __restrict__ h0,
    float* __restrict__ out, unsigned* __restrict__ hbu)
{
  const int tid   = threadIdx.x;
  const int bg    = blockIdx.x & 31;   // batch group: batches {2bg, 2bg+1}
  const int ns    = blockIdx.x >> 5;   // h-slice: outputs [64ns, 64ns+64)
  const int b0    = bg * 2;
  const int obase = ns * 64;
  const int o4    = tid & 15;          // o-block of 4 outputs
  const int kq    = tid >> 4;          // k-chunk: k in [16kq, 16kq+16)
  const int w     = tid >> 6;          // wave id 0..7
  const int lane  = tid & 63;
  const int kql   = (lane >> 4);       // k-chunk within wave, 0..3
  const int ep    = w & 1;             // batch within the finalist pair

  __shared__ float hshw[8][128];       // per-wave staged h: [w][b*64 + kloc]
  __shared__ float red[2][32][132];    // dbuf partials: [t&1][kq][b*64+o]

  // ---- W panel: rows obase+o4*4+{0..3}, cols 16kq..+16 — 16 named float4
  const float* wp = Whh + (size_t)(obase + o4 * 4) * H_ + kq * 16;
  float4 r0a = *(const float4*)(wp            );
  float4 r0b = *(const float4*)(wp         + 4);
  float4 r0c = *(const float4*)(wp         + 8);
  float4 r0d = *(const float4*)(wp        + 12);
  float4 r1a = *(const float4*)(wp +   H_     );
  float4 r1b = *(const float4*)(wp +   H_ + 4);
  float4 r1c = *(const float4*)(wp +   H_ + 8);
  float4 r1d = *(const float4*)(wp +   H_ +12);
  float4 r2a = *(const float4*)(wp + 2*H_     );
  float4 r2b = *(const float4*)(wp + 2*H_ + 4);
  float4 r2c = *(const float4*)(wp + 2*H_ + 8);
  float4 r2d = *(const float4*)(wp + 2*H_ +12);
  float4 r3a = *(const float4*)(wp + 3*H_     );
  float4 r3b = *(const float4*)(wp + 3*H_ + 4);
  float4 r3c = *(const float4*)(wp + 3*H_ + 8);
  float4 r3d = *(const float4*)(wp + 3*H_ +12);
  float4 w00 = make_float4(r0a.x, r1a.x, r2a.x, r3a.x);
  float4 w01 = make_float4(r0a.y, r1a.y, r2a.y, r3a.y);
  float4 w02 = make_float4(r0a.z, r1a.z, r2a.z, r3a.z);
  float4 w03 = make_float4(r0a.w, r1a.w, r2a.w, r3a.w);
  float4 w04 = make_float4(r0b.x, r1b.x, r2b.x, r3b.x);
  float4 w05 = make_float4(r0b.y, r1b.y, r2b.y, r3b.y);
  float4 w06 = make_float4(r0b.z, r1b.z, r2b.z, r3b.z);
  float4 w07 = make_float4(r0b.w, r1b.w, r2b.w, r3b.w);
  float4 w08 = make_float4(r0c.x, r1c.x, r2c.x, r3c.x);
  float4 w09 = make_float4(r0c.y, r1c.y, r2c.y, r3c.y);
  float4 w10 = make_float4(r0c.z, r1c.z, r2c.z, r3c.z);
  float4 w11 = make_float4(r0c.w, r1c.w, r2c.w, r3c.w);
  float4 w12 = make_float4(r0d.x, r1d.x, r2d.x, r3d.x);
  float4 w13 = make_float4(r0d.y, r1d.y, r2d.y, r3d.y);
  float4 w14 = make_float4(r0d.z, r1d.z, r2d.z, r3d.z);
  float4 w15 = make_float4(r0d.w, r1d.w, r2d.w, r3d.w);

  // Finalist output pointers (used 1-of-4 steps, rotation).
  float* outp = out + (size_t)(b0 + ep) * SH_ + obase + lane;   // +H_/step
  unsigned* hdb = hbu + (size_t)(b0 + ep) * H_ + obase + lane;  // +slot*BH_

  // Wave-local spin addresses: this wave's k-slice is [64w, 64w+64).
  const int ksl = w * 64 + lane;       // global h element within a batch

  for (int t = 0; t < S_; ++t) {
    const bool fin = ((w >> 1) == (t & 3));   // rotating finalist pair

    // xp prefetch for this step's finalists (overlaps the spin)
    float xp = 0.f;
    if (fin) xp = *outp;

    // ---- wave-local spin + stage of this wave's h slice ----
    float v0, v1;
    if (t == 0) {
      const float* hp = h0 + (size_t)b0 * H_ + ksl;
      v0 = hp[0];
      v1 = hp[H_];
    } else {
      const unsigned* hs = hbu + (t & 1) * BH_ + (size_t)b0 * H_ + ksl;
      const unsigned expct = ((unsigned)t >> 1) & 1u;
      unsigned a0 = __hip_atomic_load(hs,      __ATOMIC_RELAXED,
                                      __HIP_MEMORY_SCOPE_AGENT);
      unsigned a1 = __hip_atomic_load(hs + H_, __ATOMIC_RELAXED,
                                      __HIP_MEMORY_SCOPE_AGENT);
      while ((a0 >> 31) != expct)
        a0 = __hip_atomic_load(hs,      __ATOMIC_RELAXED,
                               __HIP_MEMORY_SCOPE_AGENT);
      while ((a1 >> 31) != expct)
        a1 = __hip_atomic_load(hs + H_, __ATOMIC_RELAXED,
                               __HIP_MEMORY_SCOPE_AGENT);
      v0 = __uint_as_float(a0 & 0x7fffffffu);
      v1 = __uint_as_float(a1 & 0x7fffffffu);
    }
    hshw[w][lane]      = v0;
    hshw[w][64 + lane] = v1;
    // same-wave DS ordering: drain writes before dependent reads
    asm volatile("s_waitcnt lgkmcnt(0)" ::: "memory");
    __builtin_amdgcn_sched_barrier(0);

    // ---- 128 FMA/thread: 2 batches x 4 outputs x 16 k (wave-local h) ----
    const float* hp0 = &hshw[w][kql * 16];
    float4 hA = *(const float4*)(hp0     );
    float4 hB = *(const float4*)(hp0 +  4);
    float4 hC = *(const float4*)(hp0 +  8);
    float4 hD = *(const float4*)(hp0 + 12);
    float4 aA = make_float4(0.f, 0.f, 0.f, 0.f);
    FMA16(aA, hA, hB, hC, hD);

    const float* hp1 = &hshw[w][64 + kql * 16];
    float4 hE = *(const float4*)(hp1     );
    float4 hF = *(const float4*)(hp1 +  4);
    float4 hG = *(const float4*)(hp1 +  8);
    float4 hH = *(const float4*)(hp1 + 12);
    float4 aB = make_float4(0.f, 0.f, 0.f, 0.f);
    FMA16(aB, hE, hF, hG, hH);

    float (*rb)[132] = red[t & 1];
    *(float4*)&rb[kq][o4 * 4]      = aA;
    *(float4*)&rb[kq][64 + o4 * 4] = aB;
    __syncthreads();                       // the ONLY barrier per step

    // ---- rotating 2-wave epilogue: tree reduce + ReLU + tagged store ----
    if (fin) {
      const int idx = ep * 64 + lane;
      float s0 = 0.f, s1 = 0.f, s2 = 0.f, s3 = 0.f;
      #pragma unroll
      for (int q = 0; q < 32; q += 4) {
        s0 += rb[q    ][idx];
        s1 += rb[q + 1][idx];
        s2 += rb[q + 2][idx];
        s3 += rb[q + 3][idx];
      }
      float pre = xp + ((s0 + s1) + (s2 + s3));
      float v = pre > 0.f ? pre : 0.f;          // ternary: never -0.0
      const unsigned tg = ((((unsigned)(t + 1)) >> 1) & 1u) << 31;
      __hip_atomic_store(hdb + ((t + 1) & 1) * BH_,
                         (__float_as_uint(v) & 0x7fffffffu) | tg,
                         __ATOMIC_RELAXED, __HIP_MEMORY_SCOPE_AGENT);
      *outp = v;                                 // out[b,t,:] = h_{t+1}
      if (t == S_ - 1)
        out[(size_t)OUT_H + (size_t)(b0 + ep) * H_ + obase + lane] = v;
    }
    outp += H_;
    // hshw: wave-private, same-wave in-order DS -> no hazard.
    // red: double-buffered; red[t&1] is reused at t+2, gated by sync2(t+1).
    // Inter-WG: the wave-local staging spin is the synchronization point.
  }
}

// ---------------------------------------------------------------------------
extern "C" void kernel_launch(void* const* d_in, const int* in_sizes, int n_in,
                              void* d_out, int out_size, void* d_ws, size_t ws_size,
                              hipStream_t stream)
{
  const float* inputs = (const float*)d_in[0];  // [B,S,I]
  const float* h0     = (const float*)d_in[1];  // [1,B,H]
  const float* w_ih   = (const float*)d_in[2];  // [H,I]
  const float* w_hh   = (const float*)d_in[3];  // [H,H]
  const float* b_ih   = (const float*)d_in[4];  // [H]
  const float* b_hh   = (const float*)d_in[5];  // [H]
  float* out = (float*)d_out;                   // [B,S,H] ++ [1,B,H] h_final

  unsigned* hbu = (unsigned*)d_ws;              // 2 tagged h slots

  dim3 g1(512, 4);
  xproj_kernel<<<g1, 256, 0, stream>>>(inputs, w_ih, b_ih, b_hh, out);
  init_kernel<<<128, 256, 0, stream>>>(hbu);
  recur_kernel<<<256, 512, 0, stream>>>(w_hh, h0, out, hbu);
}